// Round 7
// baseline (185.271 us; speedup 1.0000x reference)
//
#include <hip/hip_runtime.h>
#include <hip/hip_bf16.h>

typedef __attribute__((ext_vector_type(8))) short short8;
typedef __attribute__((ext_vector_type(16))) float f32x16;

__device__ __forceinline__ float bf2f(unsigned short h){
  union{unsigned u; float f;} c; c.u = ((unsigned)h)<<16; return c.f;
}
__device__ __forceinline__ unsigned short f2bf(float f){
  union{float f; unsigned u;} c; c.f = f;
  return (unsigned short)((c.u + 0x7fffu + ((c.u>>16)&1u))>>16);
}

// Fragment-major layout for MFMA A-operands and weights:
//   F(strip,kt,lane,j) = ((strip*6+kt)*64 + lane)*8 + j
//   holds x[strip*32 + (lane&31)][kt*16 + (lane>>5)*8 + j]
// Weights WcF[((i*12+kt)*3+t)*512 + lane*8 + j] = Wc[kt*16+(lane>>5)*8+j][t*32+(lane&31)]

// ---- fused: combined-weight build (blocks 0..depth*192) + bias fold (last depth blocks)
__global__ void k_wcb(const float* __restrict__ W0, const float* __restrict__ W1,
                      const float* __restrict__ W2, const float* __restrict__ b0,
                      const float* __restrict__ b1, const float* __restrict__ b2,
                      unsigned short* __restrict__ WcF, float* __restrict__ cvec,
                      float* __restrict__ dvec, int depth){
  int b = blockIdx.x, c = threadIdx.x;           // 96 threads
  int nwc = depth*192;
  if (b < nwc){
    int i = b/192, k = b%192;
    const float* w  = (k<96) ? (W1 + (size_t)i*96*96 + (size_t)k*96)
                             : (W0 + (size_t)i*96*96 + (size_t)(k-96)*96);
    const float* w2 = W2 + (size_t)i*192*96 + (k<96 ? 0 : 96*96);
    float s0=0.f,s1=0.f,s2=0.f,s3=0.f;
    for (int j=0;j<96;j+=4){
      s0 += w[j]   * w2[(j)*96 + c];
      s1 += w[j+1] * w2[(j+1)*96 + c];
      s2 += w[j+2] * w2[(j+2)*96 + c];
      s3 += w[j+3] * w2[(j+3)*96 + c];
    }
    float s = (s0+s1)+(s2+s3);
    int kt = k>>4, hfk=(k>>3)&1, jj=k&7;
    int t=c>>5, cl=c&31;
    WcF[(size_t)((i*12+kt)*3+t)*512 + (size_t)(hfk*32+cl)*8 + jj] = f2bf(s);
  } else {
    int i = b - nwc;
    const float* w2 = W2 + (size_t)i*192*96;
    float s = b2[i*96+c], d=0.f;
    for (int j=0;j<96;++j){
      s += b1[i*96+j]*w2[j*96+c];
      d += b0[i*96+j]*w2[(96+j)*96+c];
    }
    cvec[i*96+c]=s; dvec[i*96+c]=d;
  }
}

// ---- fused: cast f32->bf16 (row-major xb AND fragment xf) + CSR rowptr
__global__ __launch_bounds__(256) void k_prep(
    const float* __restrict__ x, unsigned short* __restrict__ xb,
    unsigned short* __restrict__ xf, const int* __restrict__ dst, int nE,
    int* __restrict__ rs, int nN, int castBlocks){
  if ((int)blockIdx.x < castBlocks){
    int tid = blockIdx.x*256 + threadIdx.x;
    if (tid >= nN*12) return;
    int n = tid/12, q = tid%12;
    const float4* src = reinterpret_cast<const float4*>(x + (size_t)n*96 + q*8);
    float4 f0 = src[0], f1 = src[1];
    uint4 o;
    o.x = (unsigned)f2bf(f0.x) | ((unsigned)f2bf(f0.y)<<16);
    o.y = (unsigned)f2bf(f0.z) | ((unsigned)f2bf(f0.w)<<16);
    o.z = (unsigned)f2bf(f1.x) | ((unsigned)f2bf(f1.y)<<16);
    o.w = (unsigned)f2bf(f1.z) | ((unsigned)f2bf(f1.w)<<16);
    *reinterpret_cast<uint4*>(xb + (size_t)n*96 + q*8) = o;
    int strip=n>>5, cl=n&31, kt=q>>1, hf=q&1;
    *reinterpret_cast<uint4*>(xf + ((size_t)(strip*6+kt)*64 + hf*32+cl)*8) = o;
  } else {
    int n = ((int)blockIdx.x - castBlocks)*256 + threadIdx.x;
    if (n > nN) return;
    int lo=0, hi=nE;
    while(lo<hi){int mid=(lo+hi)>>1; if(dst[mid]<n) lo=mid+1; else hi=mid;}
    rs[n]=lo;
  }
}

// ---- row-major bf16 -> fragment-major copy (between layers)
__global__ __launch_bounds__(256) void k_frag(
    const unsigned short* __restrict__ xb, unsigned short* __restrict__ xf, int nN){
  int tid = blockIdx.x*256+threadIdx.x;
  if (tid >= nN*12) return;
  int n=tid/12, q=tid%12;
  uint4 v = *reinterpret_cast<const uint4*>(xb + (size_t)n*96 + q*8);
  int strip=n>>5, cl=n&31, kt=q>>1, hf=q&1;
  *reinterpret_cast<uint4*>(xf + ((size_t)(strip*6+kt)*64 + hf*32+cl)*8) = v;
}

__device__ __forceinline__ void acc8(float* a, uint4 v){
  a[0] += bf2f((unsigned short)(v.x & 0xffffu));
  a[1] += bf2f((unsigned short)(v.x >> 16));
  a[2] += bf2f((unsigned short)(v.y & 0xffffu));
  a[3] += bf2f((unsigned short)(v.y >> 16));
  a[4] += bf2f((unsigned short)(v.z & 0xffffu));
  a[5] += bf2f((unsigned short)(v.z >> 16));
  a[6] += bf2f((unsigned short)(v.w & 0xffffu));
  a[7] += bf2f((unsigned short)(v.w >> 16));
}

// xa_frag[n] = sum over in-edges of x_bf16[src]; writes FRAGMENT layout directly.
__global__ __launch_bounds__(192) void k_agg(
    const unsigned short* __restrict__ xb, const int* __restrict__ esrc,
    const int* __restrict__ rs, unsigned short* __restrict__ xaf,
    int* __restrict__ deg, int nN)
{
  int n = blockIdx.x*16 + threadIdx.y;
  if (n >= nN) return;
  const int q = threadIdx.x;                 // 0..11, 8 bf16 cols each
  const unsigned short* xq = xb + q*8;
  const int e0 = rs[n], e1 = rs[n+1];
  if (q == 0) deg[n] = e1 - e0;

  float a[8] = {0,0,0,0,0,0,0,0};

  int e = e0;
  for (; e+8 <= e1; e += 8){
    int s0 = esrc[e],   s1 = esrc[e+1], s2 = esrc[e+2], s3 = esrc[e+3];
    int s4 = esrc[e+4], s5 = esrc[e+5], s6 = esrc[e+6], s7 = esrc[e+7];
    uint4 v0 = *reinterpret_cast<const uint4*>(xq + (size_t)s0*96);
    uint4 v1 = *reinterpret_cast<const uint4*>(xq + (size_t)s1*96);
    uint4 v2 = *reinterpret_cast<const uint4*>(xq + (size_t)s2*96);
    uint4 v3 = *reinterpret_cast<const uint4*>(xq + (size_t)s3*96);
    uint4 v4 = *reinterpret_cast<const uint4*>(xq + (size_t)s4*96);
    uint4 v5 = *reinterpret_cast<const uint4*>(xq + (size_t)s5*96);
    uint4 v6 = *reinterpret_cast<const uint4*>(xq + (size_t)s6*96);
    uint4 v7 = *reinterpret_cast<const uint4*>(xq + (size_t)s7*96);
    acc8(a, v0); acc8(a, v1); acc8(a, v2); acc8(a, v3);
    acc8(a, v4); acc8(a, v5); acc8(a, v6); acc8(a, v7);
  }
  for (; e+4 <= e1; e += 4){
    int s0 = esrc[e], s1 = esrc[e+1], s2 = esrc[e+2], s3 = esrc[e+3];
    uint4 v0 = *reinterpret_cast<const uint4*>(xq + (size_t)s0*96);
    uint4 v1 = *reinterpret_cast<const uint4*>(xq + (size_t)s1*96);
    uint4 v2 = *reinterpret_cast<const uint4*>(xq + (size_t)s2*96);
    uint4 v3 = *reinterpret_cast<const uint4*>(xq + (size_t)s3*96);
    acc8(a, v0); acc8(a, v1); acc8(a, v2); acc8(a, v3);
  }
  for (; e < e1; ++e){
    int s = esrc[e];
    uint4 v = *reinterpret_cast<const uint4*>(xq + (size_t)s*96);
    acc8(a, v);
  }

  uint4 o;
  o.x = (unsigned)f2bf(a[0]) | ((unsigned)f2bf(a[1]) << 16);
  o.y = (unsigned)f2bf(a[2]) | ((unsigned)f2bf(a[3]) << 16);
  o.z = (unsigned)f2bf(a[4]) | ((unsigned)f2bf(a[5]) << 16);
  o.w = (unsigned)f2bf(a[6]) | ((unsigned)f2bf(a[7]) << 16);
  int strip=n>>5, cl=n&31, kt=q>>1, hf=q&1;
  *reinterpret_cast<uint4*>(xaf + ((size_t)(strip*6+kt)*64 + hf*32+cl)*8) = o;
}

// out[row] = rownorm( x@A + xa@B + cvec + deg*dvec ); one wave = 32 rows x 96 cols
// ALL operand loads fully coalesced (fragment-major xf, xaf, WcF).
template<int LAST>
__global__ __launch_bounds__(256) void k_gemm(
    const unsigned short* __restrict__ xf, const unsigned short* __restrict__ xaf,
    const unsigned short* __restrict__ WcF, const float* __restrict__ cvec,
    const float* __restrict__ dvec, const int* __restrict__ deg,
    float* __restrict__ outf, unsigned short* __restrict__ outb, int nN)
{
  const int wid = (blockIdx.x<<2) + (threadIdx.x>>6);
  const int nstrips = (nN+31)>>5;
  if (wid >= nstrips) return;
  const int lane = threadIdx.x & 63;
  const int cl = lane & 31;
  const int hf = lane >> 5;
  const int row0 = wid << 5;

  const short8* xfp = reinterpret_cast<const short8*>(xf)  + (size_t)wid*6*64;
  const short8* xap = reinterpret_cast<const short8*>(xaf) + (size_t)wid*6*64;
  const short8* wf  = reinterpret_cast<const short8*>(WcF);

  short8 afr[12];
  #pragma unroll
  for (int kt=0; kt<6; ++kt){ afr[kt] = xfp[kt*64 + lane]; afr[6+kt] = xap[kt*64 + lane]; }

  f32x16 acc[3];
  #pragma unroll
  for (int t=0;t<3;++t){
    #pragma unroll
    for (int i=0;i<16;++i) acc[t][i] = 0.f;
  }

  #pragma unroll
  for (int kt=0; kt<12; ++kt){
    short8 a = afr[kt];
    #pragma unroll
    for (int t=0;t<3;++t){
      short8 b = wf[(kt*3+t)*64 + lane];   // coalesced 1KB wave-load
      acc[t] = __builtin_amdgcn_mfma_f32_32x32x16_bf16(a, b, acc[t], 0, 0, 0);
    }
  }

  float cv[3], dv[3];
  #pragma unroll
  for (int t=0;t<3;++t){ cv[t] = cvec[t*32+cl]; dv[t] = dvec[t*32+cl]; }

  #pragma unroll
  for (int r=0;r<16;++r){
    const int rl = (r&3) + ((r>>2)<<3) + (hf<<2);   // verified C/D row map
    const int rg = row0 + rl;
    const int rgc = rg < nN ? rg : nN-1;
    const float dgv = (float)deg[rgc];
    float v0 = acc[0][r] + cv[0] + dgv*dv[0];
    float v1 = acc[1][r] + cv[1] + dgv*dv[1];
    float v2 = acc[2][r] + cv[2] + dgv*dv[2];
    float s  = v0+v1+v2;
    float s2 = v0*v0 + v1*v1 + v2*v2;
    #pragma unroll
    for (int m=1;m<32;m<<=1){ s += __shfl_xor(s,m,64); s2 += __shfl_xor(s2,m,64); }
    float var = (s2 - s*s*(1.0f/96.0f)) * (1.0f/95.0f);   // ddof=1
    float sc  = 1.0f / sqrtf(var);
    if (rg < nN){
      if (LAST){
        float* o = outf + (size_t)rg*96;
        o[cl] = v0*sc; o[32+cl] = v1*sc; o[64+cl] = v2*sc;
      } else {
        unsigned short* o = outb + (size_t)rg*96;
        o[cl] = f2bf(v0*sc); o[32+cl] = f2bf(v1*sc); o[64+cl] = f2bf(v2*sc);
      }
    }
  }
}

extern "C" void kernel_launch(void* const* d_in, const int* in_sizes, int n_in,
                              void* d_out, int out_size, void* d_ws, size_t ws_size,
                              hipStream_t stream)
{
  const float* x   = (const float*)d_in[0];
  const float* W0  = (const float*)d_in[1];
  const float* b0  = (const float*)d_in[2];
  const float* W1  = (const float*)d_in[3];
  const float* b1  = (const float*)d_in[4];
  const float* W2  = (const float*)d_in[5];
  const float* b2  = (const float*)d_in[6];
  const int* esrc  = (const int*)d_in[7];
  const int* edst  = (const int*)d_in[8];
  const int nN = in_sizes[0] / 96;
  const int nE = in_sizes[7];
  const int depth = in_sizes[1] / (96*96);
  float* out = (float*)d_out;

  const int nstrips = (nN+31)/32;

  char* p = (char*)d_ws;
  auto alloc = [&](size_t bytes)->char*{ char* r = p; p += (bytes + 255) & ~(size_t)255; return r; };
  unsigned short* WcF  = (unsigned short*)alloc((size_t)depth*12*3*512*2);
  float* cvec          = (float*)alloc((size_t)depth*96*4);
  float* dvec          = (float*)alloc((size_t)depth*96*4);
  int* rs              = (int*)alloc((size_t)(nN+1)*4);
  int* deg             = (int*)alloc((size_t)nN*4);
  unsigned short* xb0  = (unsigned short*)alloc((size_t)nN*96*2);
  unsigned short* xb1  = (unsigned short*)alloc((size_t)nN*96*2);
  unsigned short* xf   = (unsigned short*)alloc((size_t)nstrips*3072*2);
  unsigned short* xaf  = (unsigned short*)alloc((size_t)nstrips*3072*2);

  k_wcb<<<dim3(depth*192+depth), dim3(96), 0, stream>>>(W0, W1, W2, b0, b1, b2,
                                                        WcF, cvec, dvec, depth);
  const int castBlocks = (nN*12+255)/256;
  const int rpBlocks   = (nN+1+255)/256;
  k_prep<<<dim3(castBlocks+rpBlocks), dim3(256), 0, stream>>>(x, xb0, xf, edst, nE, rs, nN, castBlocks);

  const int aggGrid  = (nN+15)/16;
  const int gemmGrid = (nstrips+3)/4;
  const int fragGrid = castBlocks;

  unsigned short* cur = xb0;
  unsigned short* nxt = xb1;
  for (int i=0; i<depth; ++i){
    k_agg<<<dim3(aggGrid), dim3(12,16), 0, stream>>>(cur, esrc, rs, xaf, deg, nN);
    if (i == depth-1){
      k_gemm<1><<<dim3(gemmGrid), dim3(256), 0, stream>>>(
          xf, xaf, WcF + (size_t)i*12*3*512, cvec + i*96, dvec + i*96, deg,
          out, (unsigned short*)nullptr, nN);
    } else {
      k_gemm<0><<<dim3(gemmGrid), dim3(256), 0, stream>>>(
          xf, xaf, WcF + (size_t)i*12*3*512, cvec + i*96, dvec + i*96, deg,
          (float*)nullptr, nxt, nN);
      k_frag<<<dim3(fragGrid), dim3(256), 0, stream>>>(nxt, xf, nN);
      unsigned short* t = cur; cur = nxt; nxt = t;
    }
  }
}

// Round 8
// 177.784 us; speedup vs baseline: 1.0421x; 1.0421x over previous
//
#include <hip/hip_runtime.h>
#include <hip/hip_bf16.h>

typedef __attribute__((ext_vector_type(8))) short short8;
typedef __attribute__((ext_vector_type(16))) float f32x16;

__device__ __forceinline__ float bf2f(unsigned short h){
  union{unsigned u; float f;} c; c.u = ((unsigned)h)<<16; return c.f;
}
__device__ __forceinline__ unsigned short f2bf(float f){
  union{float f; unsigned u;} c; c.f = f;
  return (unsigned short)((c.u + 0x7fffu + ((c.u>>16)&1u))>>16);
}

// Fragment-major layout (MFMA A-operand / weights):
//   F(strip,kt,lane,j) = ((strip*6+kt)*64 + lane)*8 + j
//   holds x[strip*32 + (lane&31)][kt*16 + (lane>>5)*8 + j]
// WcF[((i*12+kt)*3+t)*512 + lane*8 + j] = Wc[kt*16+(lane>>5)*8+j][t*32+(lane&31)]

// ---- ONE fused prep launch: [0,nwc) weight-combine | [nwc,nwc+depth) bias |
//      [.., +castBlocks) cast->xb,xf | [.., +rpBlocks) CSR rowptr
__global__ __launch_bounds__(256) void k_pre(
    const float* __restrict__ x,  const float* __restrict__ W0,
    const float* __restrict__ W1, const float* __restrict__ W2,
    const float* __restrict__ b0, const float* __restrict__ b1,
    const float* __restrict__ b2, const int* __restrict__ dst,
    unsigned short* __restrict__ WcF, float* __restrict__ cvec,
    float* __restrict__ dvec, unsigned short* __restrict__ xb,
    unsigned short* __restrict__ xf, int* __restrict__ rs,
    int nN, int nE, int depth, int castBlocks)
{
  const int b = blockIdx.x, tid = threadIdx.x;
  const int nwc = depth*192;
  if (b < nwc){
    __shared__ float sm[96];
    int i = b/192, k = b%192;
    float s = 0.f;
    if (tid < 192){
      int c = tid % 96, jh = tid / 96;
      const float* w  = (k<96) ? (W1 + (size_t)i*9216 + (size_t)k*96)
                               : (W0 + (size_t)i*9216 + (size_t)(k-96)*96);
      const float* w2 = W2 + (size_t)i*18432 + (k<96 ? 0 : 9216);
      int j0 = jh*48;
      float s0=0.f,s1=0.f,s2=0.f,s3=0.f;
      for (int j=j0;j<j0+48;j+=4){
        s0 += w[j]   * w2[(j)*96 + c];
        s1 += w[j+1] * w2[(j+1)*96 + c];
        s2 += w[j+2] * w2[(j+2)*96 + c];
        s3 += w[j+3] * w2[(j+3)*96 + c];
      }
      s = (s0+s1)+(s2+s3);
      if (jh==1) sm[c] = s;
    }
    __syncthreads();
    if (tid < 96){
      float tot = s + sm[tid];
      int kt=k>>4, hfk=(k>>3)&1, jj=k&7;
      int t=tid>>5, cl=tid&31;
      WcF[(size_t)((i*12+kt)*3+t)*512 + (size_t)(hfk*32+cl)*8 + jj] = f2bf(tot);
    }
  } else if (b < nwc + depth){
    int i = b - nwc;
    if (tid < 96){
      const float* w2 = W2 + (size_t)i*18432;
      float s = b2[i*96+tid], d=0.f;
      for (int j=0;j<96;++j){
        s += b1[i*96+j]*w2[j*96+tid];
        d += b0[i*96+j]*w2[(96+j)*96+tid];
      }
      cvec[i*96+tid]=s; dvec[i*96+tid]=d;
    }
  } else if (b < nwc + depth + castBlocks){
    int t2 = (b - nwc - depth)*256 + tid;
    if (t2 >= nN*12) return;
    int n = t2/12, q = t2%12;
    const float4* src = reinterpret_cast<const float4*>(x + (size_t)n*96 + q*8);
    float4 f0 = src[0], f1 = src[1];
    uint4 o;
    o.x = (unsigned)f2bf(f0.x) | ((unsigned)f2bf(f0.y)<<16);
    o.y = (unsigned)f2bf(f0.z) | ((unsigned)f2bf(f0.w)<<16);
    o.z = (unsigned)f2bf(f1.x) | ((unsigned)f2bf(f1.y)<<16);
    o.w = (unsigned)f2bf(f1.z) | ((unsigned)f2bf(f1.w)<<16);
    *reinterpret_cast<uint4*>(xb + (size_t)n*96 + q*8) = o;
    int strip=n>>5, cl=n&31, kt=q>>1, hf=q&1;
    *reinterpret_cast<uint4*>(xf + ((size_t)(strip*6+kt)*64 + hf*32+cl)*8) = o;
  } else {
    int n = (b - nwc - depth - castBlocks)*256 + tid;
    if (n > nN) return;
    int lo=0, hi=nE;
    while(lo<hi){int mid=(lo+hi)>>1; if(dst[mid]<n) lo=mid+1; else hi=mid;}
    rs[n]=lo;
  }
}

__device__ __forceinline__ void acc8(float* a, uint4 v){
  a[0] += bf2f((unsigned short)(v.x & 0xffffu));
  a[1] += bf2f((unsigned short)(v.x >> 16));
  a[2] += bf2f((unsigned short)(v.y & 0xffffu));
  a[3] += bf2f((unsigned short)(v.y >> 16));
  a[4] += bf2f((unsigned short)(v.z & 0xffffu));
  a[5] += bf2f((unsigned short)(v.z >> 16));
  a[6] += bf2f((unsigned short)(v.w & 0xffffu));
  a[7] += bf2f((unsigned short)(v.w >> 16));
}

// xa_frag[n] = sum over in-edges of x_bf16[src]; 12 thr/node x 16B, 8-way MLP unroll.
__global__ __launch_bounds__(192) void k_agg(
    const unsigned short* __restrict__ xb, const int* __restrict__ esrc,
    const int* __restrict__ rs, unsigned short* __restrict__ xaf,
    int* __restrict__ deg, int nN)
{
  int n = blockIdx.x*16 + threadIdx.y;
  if (n >= nN) return;
  const int q = threadIdx.x;                 // 0..11, 8 bf16 cols each
  const unsigned short* xq = xb + q*8;
  const int e0 = rs[n], e1 = rs[n+1];
  if (q == 0) deg[n] = e1 - e0;

  float a[8] = {0,0,0,0,0,0,0,0};

  int e = e0;
  for (; e+8 <= e1; e += 8){
    int s0 = esrc[e],   s1 = esrc[e+1], s2 = esrc[e+2], s3 = esrc[e+3];
    int s4 = esrc[e+4], s5 = esrc[e+5], s6 = esrc[e+6], s7 = esrc[e+7];
    uint4 v0 = *reinterpret_cast<const uint4*>(xq + (size_t)s0*96);
    uint4 v1 = *reinterpret_cast<const uint4*>(xq + (size_t)s1*96);
    uint4 v2 = *reinterpret_cast<const uint4*>(xq + (size_t)s2*96);
    uint4 v3 = *reinterpret_cast<const uint4*>(xq + (size_t)s3*96);
    uint4 v4 = *reinterpret_cast<const uint4*>(xq + (size_t)s4*96);
    uint4 v5 = *reinterpret_cast<const uint4*>(xq + (size_t)s5*96);
    uint4 v6 = *reinterpret_cast<const uint4*>(xq + (size_t)s6*96);
    uint4 v7 = *reinterpret_cast<const uint4*>(xq + (size_t)s7*96);
    acc8(a, v0); acc8(a, v1); acc8(a, v2); acc8(a, v3);
    acc8(a, v4); acc8(a, v5); acc8(a, v6); acc8(a, v7);
  }
  for (; e+4 <= e1; e += 4){
    int s0 = esrc[e], s1 = esrc[e+1], s2 = esrc[e+2], s3 = esrc[e+3];
    uint4 v0 = *reinterpret_cast<const uint4*>(xq + (size_t)s0*96);
    uint4 v1 = *reinterpret_cast<const uint4*>(xq + (size_t)s1*96);
    uint4 v2 = *reinterpret_cast<const uint4*>(xq + (size_t)s2*96);
    uint4 v3 = *reinterpret_cast<const uint4*>(xq + (size_t)s3*96);
    acc8(a, v0); acc8(a, v1); acc8(a, v2); acc8(a, v3);
  }
  for (; e < e1; ++e){
    int s = esrc[e];
    uint4 v = *reinterpret_cast<const uint4*>(xq + (size_t)s*96);
    acc8(a, v);
  }

  uint4 o;
  o.x = (unsigned)f2bf(a[0]) | ((unsigned)f2bf(a[1]) << 16);
  o.y = (unsigned)f2bf(a[2]) | ((unsigned)f2bf(a[3]) << 16);
  o.z = (unsigned)f2bf(a[4]) | ((unsigned)f2bf(a[5]) << 16);
  o.w = (unsigned)f2bf(a[6]) | ((unsigned)f2bf(a[7]) << 16);
  int strip=n>>5, cl=n&31, kt=q>>1, hf=q&1;
  *reinterpret_cast<uint4*>(xaf + ((size_t)(strip*6+kt)*64 + hf*32+cl)*8) = o;
}

// out[row] = rownorm( x@A + xa@B + cvec + deg*dvec ); one wave = 32 rows x 96 cols.
// Non-LAST epilogue writes BOTH row-major (next gather) and fragment (next gemm A).
template<int LAST>
__global__ __launch_bounds__(256) void k_gemm(
    const unsigned short* __restrict__ xf, const unsigned short* __restrict__ xaf,
    const unsigned short* __restrict__ WcF, const float* __restrict__ cvec,
    const float* __restrict__ dvec, const int* __restrict__ deg,
    float* __restrict__ outf, unsigned short* __restrict__ outb,
    unsigned short* __restrict__ xfo, int nN)
{
  const int wid = (blockIdx.x<<2) + (threadIdx.x>>6);
  const int nstrips = (nN+31)>>5;
  if (wid >= nstrips) return;
  const int lane = threadIdx.x & 63;
  const int cl = lane & 31;
  const int hf = lane >> 5;
  const int row0 = wid << 5;

  const short8* xfp = reinterpret_cast<const short8*>(xf)  + (size_t)wid*6*64;
  const short8* xap = reinterpret_cast<const short8*>(xaf) + (size_t)wid*6*64;
  const short8* wf  = reinterpret_cast<const short8*>(WcF);

  short8 afr[12];
  #pragma unroll
  for (int kt=0; kt<6; ++kt){ afr[kt] = xfp[kt*64 + lane]; afr[6+kt] = xap[kt*64 + lane]; }

  f32x16 acc[3];
  #pragma unroll
  for (int t=0;t<3;++t){
    #pragma unroll
    for (int i=0;i<16;++i) acc[t][i] = 0.f;
  }

  #pragma unroll
  for (int kt=0; kt<12; ++kt){
    short8 a = afr[kt];
    #pragma unroll
    for (int t=0;t<3;++t){
      short8 b = wf[(kt*3+t)*64 + lane];   // coalesced 1KB wave-load
      acc[t] = __builtin_amdgcn_mfma_f32_32x32x16_bf16(a, b, acc[t], 0, 0, 0);
    }
  }

  float cv[3], dv[3];
  #pragma unroll
  for (int t=0;t<3;++t){ cv[t] = cvec[t*32+cl]; dv[t] = dvec[t*32+cl]; }

  // fragment-write address pieces (cols {cl, 32+cl, 64+cl} -> kt = cl>>4 + {0,2,4})
  const int jj  = cl & 7;
  const int hfd = (cl >> 3) & 1;
  const int ktb = cl >> 4;

  #pragma unroll
  for (int r=0;r<16;++r){
    const int rl = (r&3) + ((r>>2)<<3) + (hf<<2);   // verified C/D row map
    const int rg = row0 + rl;
    const int rgc = rg < nN ? rg : nN-1;
    const float dgv = (float)deg[rgc];
    float v0 = acc[0][r] + cv[0] + dgv*dv[0];
    float v1 = acc[1][r] + cv[1] + dgv*dv[1];
    float v2 = acc[2][r] + cv[2] + dgv*dv[2];
    float s  = v0+v1+v2;
    float s2 = v0*v0 + v1*v1 + v2*v2;
    #pragma unroll
    for (int m=1;m<32;m<<=1){ s += __shfl_xor(s,m,64); s2 += __shfl_xor(s2,m,64); }
    float var = (s2 - s*s*(1.0f/96.0f)) * (1.0f/95.0f);   // ddof=1
    float sc  = 1.0f / sqrtf(var);
    if (rg < nN){
      if (LAST){
        float* o = outf + (size_t)rg*96;
        o[cl] = v0*sc; o[32+cl] = v1*sc; o[64+cl] = v2*sc;
      } else {
        unsigned short h0 = f2bf(v0*sc), h1 = f2bf(v1*sc), h2 = f2bf(v2*sc);
        unsigned short* o = outb + (size_t)rg*96;
        o[cl] = h0; o[32+cl] = h1; o[64+cl] = h2;
        size_t base = (size_t)wid*3072 + (size_t)(hfd*32 + rl)*8 + jj;
        xfo[base + (size_t)(ktb  )*512] = h0;
        xfo[base + (size_t)(ktb+2)*512] = h1;
        xfo[base + (size_t)(ktb+4)*512] = h2;
      }
    }
  }
}

extern "C" void kernel_launch(void* const* d_in, const int* in_sizes, int n_in,
                              void* d_out, int out_size, void* d_ws, size_t ws_size,
                              hipStream_t stream)
{
  const float* x   = (const float*)d_in[0];
  const float* W0  = (const float*)d_in[1];
  const float* b0  = (const float*)d_in[2];
  const float* W1  = (const float*)d_in[3];
  const float* b1  = (const float*)d_in[4];
  const float* W2  = (const float*)d_in[5];
  const float* b2  = (const float*)d_in[6];
  const int* esrc  = (const int*)d_in[7];
  const int* edst  = (const int*)d_in[8];
  const int nN = in_sizes[0] / 96;
  const int nE = in_sizes[7];
  const int depth = in_sizes[1] / (96*96);
  float* out = (float*)d_out;

  const int nstrips = (nN+31)/32;

  char* p = (char*)d_ws;
  auto alloc = [&](size_t bytes)->char*{ char* r = p; p += (bytes + 255) & ~(size_t)255; return r; };
  unsigned short* WcF  = (unsigned short*)alloc((size_t)depth*12*3*512*2);
  float* cvec          = (float*)alloc((size_t)depth*96*4);
  float* dvec          = (float*)alloc((size_t)depth*96*4);
  int* rs              = (int*)alloc((size_t)(nN+1)*4);
  int* deg             = (int*)alloc((size_t)nN*4);
  unsigned short* xb0  = (unsigned short*)alloc((size_t)nN*96*2);
  unsigned short* xb1  = (unsigned short*)alloc((size_t)nN*96*2);
  unsigned short* xf   = (unsigned short*)alloc((size_t)nstrips*3072*2);
  unsigned short* xaf  = (unsigned short*)alloc((size_t)nstrips*3072*2);

  const int castBlocks = (nN*12+255)/256;
  const int rpBlocks   = (nN+1+255)/256;
  const int preGrid    = depth*192 + depth + castBlocks + rpBlocks;
  k_pre<<<dim3(preGrid), dim3(256), 0, stream>>>(
      x, W0, W1, W2, b0, b1, b2, edst, WcF, cvec, dvec, xb0, xf, rs,
      nN, nE, depth, castBlocks);

  const int aggGrid  = (nN+15)/16;
  const int gemmGrid = (nstrips+3)/4;

  unsigned short* cur = xb0;
  unsigned short* nxt = xb1;
  for (int i=0; i<depth; ++i){
    k_agg<<<dim3(aggGrid), dim3(12,16), 0, stream>>>(cur, esrc, rs, xaf, deg, nN);
    if (i == depth-1){
      k_gemm<1><<<dim3(gemmGrid), dim3(256), 0, stream>>>(
          xf, xaf, WcF + (size_t)i*12*3*512, cvec + i*96, dvec + i*96, deg,
          out, (unsigned short*)nullptr, (unsigned short*)nullptr, nN);
    } else {
      k_gemm<0><<<dim3(gemmGrid), dim3(256), 0, stream>>>(
          xf, xaf, WcF + (size_t)i*12*3*512, cvec + i*96, dvec + i*96, deg,
          (float*)nullptr, nxt, xf, nN);
      unsigned short* t = cur; cur = nxt; nxt = t;
    }
  }
}

// Round 10
// 171.134 us; speedup vs baseline: 1.0826x; 1.0389x over previous
//
#include <hip/hip_runtime.h>
#include <hip/hip_bf16.h>

typedef __attribute__((ext_vector_type(8))) short short8;
typedef __attribute__((ext_vector_type(16))) float f32x16;

__device__ __forceinline__ float bf2f(unsigned short h){
  union{unsigned u; float f;} c; c.u = ((unsigned)h)<<16; return c.f;
}
__device__ __forceinline__ unsigned short f2bf(float f){
  union{float f; unsigned u;} c; c.f = f;
  return (unsigned short)((c.u + 0x7fffu + ((c.u>>16)&1u))>>16);
}

// Fragment-major layout (MFMA A-operand / weights):
//   F(strip,kt,lane,j) = ((strip*6+kt)*64 + lane)*8 + j
//   holds x[strip*32 + (lane&31)][kt*16 + (lane>>5)*8 + j]
// WcF[((i*12+kt)*3+t)*512 + lane*8 + j] = Wc[kt*16+(lane>>5)*8+j][t*32+(lane&31)]

// ---- ONE fused prep launch: weight-combine | bias | cast->xb,xf | CSR rowptr
__global__ __launch_bounds__(256) void k_pre(
    const float* __restrict__ x,  const float* __restrict__ W0,
    const float* __restrict__ W1, const float* __restrict__ W2,
    const float* __restrict__ b0, const float* __restrict__ b1,
    const float* __restrict__ b2, const int* __restrict__ dst,
    unsigned short* __restrict__ WcF, float* __restrict__ cvec,
    float* __restrict__ dvec, unsigned short* __restrict__ xb,
    unsigned short* __restrict__ xf, int* __restrict__ rs,
    int nN, int nE, int depth, int castBlocks)
{
  const int b = blockIdx.x, tid = threadIdx.x;
  const int nwc = depth*192;
  if (b < nwc){
    __shared__ float sm[96];
    int i = b/192, k = b%192;
    float s = 0.f;
    if (tid < 192){
      int c = tid % 96, jh = tid / 96;
      const float* w  = (k<96) ? (W1 + (size_t)i*9216 + (size_t)k*96)
                               : (W0 + (size_t)i*9216 + (size_t)(k-96)*96);
      const float* w2 = W2 + (size_t)i*18432 + (k<96 ? 0 : 9216);
      int j0 = jh*48;
      float s0=0.f,s1=0.f,s2=0.f,s3=0.f;
      for (int j=j0;j<j0+48;j+=4){
        s0 += w[j]   * w2[(j)*96 + c];
        s1 += w[j+1] * w2[(j+1)*96 + c];
        s2 += w[j+2] * w2[(j+2)*96 + c];
        s3 += w[j+3] * w2[(j+3)*96 + c];
      }
      s = (s0+s1)+(s2+s3);
      if (jh==1) sm[c] = s;
    }
    __syncthreads();
    if (tid < 96){
      float tot = s + sm[tid];
      int kt=k>>4, hfk=(k>>3)&1, jj=k&7;
      int t=tid>>5, cl=tid&31;
      WcF[(size_t)((i*12+kt)*3+t)*512 + (size_t)(hfk*32+cl)*8 + jj] = f2bf(tot);
    }
  } else if (b < nwc + depth){
    int i = b - nwc;
    if (tid < 96){
      const float* w2 = W2 + (size_t)i*18432;
      float s = b2[i*96+tid], d=0.f;
      for (int j=0;j<96;++j){
        s += b1[i*96+j]*w2[j*96+tid];
        d += b0[i*96+j]*w2[(96+j)*96+tid];
      }
      cvec[i*96+tid]=s; dvec[i*96+tid]=d;
    }
  } else if (b < nwc + depth + castBlocks){
    int t2 = (b - nwc - depth)*256 + tid;
    if (t2 >= nN*12) return;
    int n = t2/12, q = t2%12;
    const float4* src = reinterpret_cast<const float4*>(x + (size_t)n*96 + q*8);
    float4 f0 = src[0], f1 = src[1];
    uint4 o;
    o.x = (unsigned)f2bf(f0.x) | ((unsigned)f2bf(f0.y)<<16);
    o.y = (unsigned)f2bf(f0.z) | ((unsigned)f2bf(f0.w)<<16);
    o.z = (unsigned)f2bf(f1.x) | ((unsigned)f2bf(f1.y)<<16);
    o.w = (unsigned)f2bf(f1.z) | ((unsigned)f2bf(f1.w)<<16);
    *reinterpret_cast<uint4*>(xb + (size_t)n*96 + q*8) = o;
    int strip=n>>5, cl=n&31, kt=q>>1, hf=q&1;
    *reinterpret_cast<uint4*>(xf + ((size_t)(strip*6+kt)*64 + hf*32+cl)*8) = o;
  } else {
    int n = (b - nwc - depth - castBlocks)*256 + tid;
    if (n > nN) return;
    int lo=0, hi=nE;
    while(lo<hi){int mid=(lo+hi)>>1; if(dst[mid]<n) lo=mid+1; else hi=mid;}
    rs[n]=lo;
  }
}

__device__ __forceinline__ void acc8(float* a, uint4 v){
  a[0] += bf2f((unsigned short)(v.x & 0xffffu));
  a[1] += bf2f((unsigned short)(v.x >> 16));
  a[2] += bf2f((unsigned short)(v.y & 0xffffu));
  a[3] += bf2f((unsigned short)(v.y >> 16));
  a[4] += bf2f((unsigned short)(v.z & 0xffffu));
  a[5] += bf2f((unsigned short)(v.z >> 16));
  a[6] += bf2f((unsigned short)(v.w & 0xffffu));
  a[7] += bf2f((unsigned short)(v.w >> 16));
}

// ---- fused per-layer kernel: one block (384 thr) per 32-row strip.
// Phase 1: gather strip's in-edges (12 thr/node x 16B, 8-way MLP, LDS edge stage)
//          -> xa tile in LDS (fragment layout).
// Phase 2: wave 0 does 192x96 MFMA GEMM + bias/deg + rowstd + stores.
#define ECAP 2048
template<int LAST>
__global__ __launch_bounds__(384) void k_fused(
    const unsigned short* __restrict__ xb, const unsigned short* __restrict__ xf,
    const int* __restrict__ esrc, const int* __restrict__ rs,
    const unsigned short* __restrict__ WcF, const float* __restrict__ cvec,
    const float* __restrict__ dvec,
    float* __restrict__ outf, unsigned short* __restrict__ outb,
    unsigned short* __restrict__ xfo, int nN)
{
  __shared__ short aL[6*64*8];      // xa fragment tile, 6 KB
  __shared__ int   eL[ECAP];        // staged edge sources
  __shared__ int   rsL[33];

  const int tid = threadIdx.x;
  const int wid = blockIdx.x;       // strip id
  const int row0 = wid << 5;

  if (tid < 33){
    int nidx = row0 + tid; if (nidx > nN) nidx = nN;
    rsL[tid] = rs[nidx];
  }
  __syncthreads();
  const int base = rsL[0];
  const int cnt  = rsL[32] - base;

  // gather mapping
  const int nl = tid / 12;            // 0..31
  const int q  = tid - nl*12;         // 0..11
  const unsigned short* xq = xb + q*8;
  const int e0 = rsL[nl], e1 = rsL[nl+1];
  float a[8] = {0,0,0,0,0,0,0,0};

  for (int cb = base; cb < base + cnt; cb += ECAP){
    const int clen = min(ECAP, base + cnt - cb);
    if (cb != base) __syncthreads();            // eL reuse guard
    for (int i = tid; i < clen; i += 384) eL[i] = esrc[cb + i];
    __syncthreads();
    int e  = max(e0, cb);
    int hi = min(e1, cb + clen);
    const int* ep = eL - cb;
    for (; e+8 <= hi; e += 8){
      int s0=ep[e],s1=ep[e+1],s2=ep[e+2],s3=ep[e+3];
      int s4=ep[e+4],s5=ep[e+5],s6=ep[e+6],s7=ep[e+7];
      uint4 v0=*reinterpret_cast<const uint4*>(xq+(size_t)s0*96);
      uint4 v1=*reinterpret_cast<const uint4*>(xq+(size_t)s1*96);
      uint4 v2=*reinterpret_cast<const uint4*>(xq+(size_t)s2*96);
      uint4 v3=*reinterpret_cast<const uint4*>(xq+(size_t)s3*96);
      uint4 v4=*reinterpret_cast<const uint4*>(xq+(size_t)s4*96);
      uint4 v5=*reinterpret_cast<const uint4*>(xq+(size_t)s5*96);
      uint4 v6=*reinterpret_cast<const uint4*>(xq+(size_t)s6*96);
      uint4 v7=*reinterpret_cast<const uint4*>(xq+(size_t)s7*96);
      acc8(a,v0); acc8(a,v1); acc8(a,v2); acc8(a,v3);
      acc8(a,v4); acc8(a,v5); acc8(a,v6); acc8(a,v7);
    }
    for (; e+4 <= hi; e += 4){
      int s0=ep[e],s1=ep[e+1],s2=ep[e+2],s3=ep[e+3];
      uint4 v0=*reinterpret_cast<const uint4*>(xq+(size_t)s0*96);
      uint4 v1=*reinterpret_cast<const uint4*>(xq+(size_t)s1*96);
      uint4 v2=*reinterpret_cast<const uint4*>(xq+(size_t)s2*96);
      uint4 v3=*reinterpret_cast<const uint4*>(xq+(size_t)s3*96);
      acc8(a,v0); acc8(a,v1); acc8(a,v2); acc8(a,v3);
    }
    for (; e < hi; ++e){
      uint4 v=*reinterpret_cast<const uint4*>(xq+(size_t)ep[e]*96);
      acc8(a,v);
    }
  }

  // write xa tile to LDS in fragment layout
  {
    uint4 o;
    o.x=(unsigned)f2bf(a[0])|((unsigned)f2bf(a[1])<<16);
    o.y=(unsigned)f2bf(a[2])|((unsigned)f2bf(a[3])<<16);
    o.z=(unsigned)f2bf(a[4])|((unsigned)f2bf(a[5])<<16);
    o.w=(unsigned)f2bf(a[6])|((unsigned)f2bf(a[7])<<16);
    *reinterpret_cast<uint4*>(&aL[((q>>1)*64 + (q&1)*32 + nl)<<3]) = o;
  }
  __syncthreads();

  if (tid >= 64) return;

  // ---- phase 2: GEMM (wave 0)
  const int lane = tid;
  const int cl = lane & 31;
  const int hf = lane >> 5;

  const short8* xfp = reinterpret_cast<const short8*>(xf) + (size_t)wid*384;
  const short8* aLs = reinterpret_cast<const short8*>(aL);
  const short8* wf  = reinterpret_cast<const short8*>(WcF);

  short8 afr[6];
  #pragma unroll
  for (int kt=0; kt<6; ++kt) afr[kt] = xfp[kt*64 + lane];

  f32x16 acc[3];
  #pragma unroll
  for (int t=0;t<3;++t){
    #pragma unroll
    for (int i=0;i<16;++i) acc[t][i] = 0.f;
  }

  #pragma unroll
  for (int kt=0; kt<12; ++kt){
    short8 av = (kt < 6) ? afr[kt] : aLs[(kt-6)*64 + lane];
    #pragma unroll
    for (int t=0;t<3;++t){
      short8 b = wf[(kt*3+t)*64 + lane];
      acc[t] = __builtin_amdgcn_mfma_f32_32x32x16_bf16(av, b, acc[t], 0, 0, 0);
    }
  }

  float cv[3], dv[3];
  #pragma unroll
  for (int t=0;t<3;++t){ cv[t] = cvec[t*32+cl]; dv[t] = dvec[t*32+cl]; }

  const int jj  = cl & 7;
  const int hfd = (cl >> 3) & 1;
  const int ktb = cl >> 4;

  #pragma unroll
  for (int r=0;r<16;++r){
    const int rl = (r&3) + ((r>>2)<<3) + (hf<<2);   // verified C/D row map
    const int rg = row0 + rl;
    const float dgv = (float)(rsL[rl+1] - rsL[rl]);
    float v0 = acc[0][r] + cv[0] + dgv*dv[0];
    float v1 = acc[1][r] + cv[1] + dgv*dv[1];
    float v2 = acc[2][r] + cv[2] + dgv*dv[2];
    float s  = v0+v1+v2;
    float s2 = v0*v0 + v1*v1 + v2*v2;
    #pragma unroll
    for (int m=1;m<32;m<<=1){ s += __shfl_xor(s,m,64); s2 += __shfl_xor(s2,m,64); }
    float var = (s2 - s*s*(1.0f/96.0f)) * (1.0f/95.0f);   // ddof=1
    float sc  = 1.0f / sqrtf(var);
    if (rg < nN){
      if (LAST){
        float* o = outf + (size_t)rg*96;
        o[cl] = v0*sc; o[32+cl] = v1*sc; o[64+cl] = v2*sc;
      } else {
        unsigned short h0 = f2bf(v0*sc), h1 = f2bf(v1*sc), h2 = f2bf(v2*sc);
        unsigned short* o = outb + (size_t)rg*96;
        o[cl] = h0; o[32+cl] = h1; o[64+cl] = h2;
        size_t bofs = (size_t)wid*3072 + (size_t)(hfd*32 + rl)*8 + jj;
        xfo[bofs + (size_t)(ktb  )*512] = h0;
        xfo[bofs + (size_t)(ktb+2)*512] = h1;
        xfo[bofs + (size_t)(ktb+4)*512] = h2;
      }
    }
  }
}

extern "C" void kernel_launch(void* const* d_in, const int* in_sizes, int n_in,
                              void* d_out, int out_size, void* d_ws, size_t ws_size,
                              hipStream_t stream)
{
  const float* x   = (const float*)d_in[0];
  const float* W0  = (const float*)d_in[1];
  const float* b0  = (const float*)d_in[2];
  const float* W1  = (const float*)d_in[3];
  const float* b1  = (const float*)d_in[4];
  const float* W2  = (const float*)d_in[5];
  const float* b2  = (const float*)d_in[6];
  const int* esrc  = (const int*)d_in[7];
  const int* edst  = (const int*)d_in[8];
  const int nN = in_sizes[0] / 96;
  const int nE = in_sizes[7];
  const int depth = in_sizes[1] / (96*96);
  float* out = (float*)d_out;

  const int nstrips = (nN+31)/32;

  char* p = (char*)d_ws;
  auto alloc = [&](size_t bytes)->char*{ char* r = p; p += (bytes + 255) & ~(size_t)255; return r; };
  unsigned short* WcF  = (unsigned short*)alloc((size_t)depth*12*3*512*2);
  float* cvec          = (float*)alloc((size_t)depth*96*4);
  float* dvec          = (float*)alloc((size_t)depth*96*4);
  int* rs              = (int*)alloc((size_t)(nN+1)*4);
  unsigned short* xb0  = (unsigned short*)alloc((size_t)nN*96*2);
  unsigned short* xb1  = (unsigned short*)alloc((size_t)nN*96*2);
  unsigned short* xf   = (unsigned short*)alloc((size_t)nstrips*3072*2);

  const int castBlocks = (nN*12+255)/256;
  const int rpBlocks   = (nN+1+255)/256;
  const int preGrid    = depth*192 + depth + castBlocks + rpBlocks;
  k_pre<<<dim3(preGrid), dim3(256), 0, stream>>>(
      x, W0, W1, W2, b0, b1, b2, edst, WcF, cvec, dvec, xb0, xf, rs,
      nN, nE, depth, castBlocks);

  unsigned short* cur = xb0;
  unsigned short* nxt = xb1;
  for (int i=0; i<depth; ++i){
    if (i == depth-1){
      k_fused<1><<<dim3(nstrips), dim3(384), 0, stream>>>(
          cur, xf, esrc, rs, WcF + (size_t)i*12*3*512, cvec + i*96, dvec + i*96,
          out, (unsigned short*)nullptr, (unsigned short*)nullptr, nN);
    } else {
      k_fused<0><<<dim3(nstrips), dim3(384), 0, stream>>>(
          cur, xf, esrc, rs, WcF + (size_t)i*12*3*512, cvec + i*96, dvec + i*96,
          (float*)nullptr, nxt, xf, nN);
      unsigned short* t = cur; cur = nxt; nxt = t;
    }
  }
}

// Round 12
// 167.905 us; speedup vs baseline: 1.1034x; 1.0192x over previous
//
#include <hip/hip_runtime.h>
#include <hip/hip_bf16.h>

typedef __attribute__((ext_vector_type(8))) short short8;
typedef __attribute__((ext_vector_type(16))) float f32x16;

__device__ __forceinline__ float bf2f(unsigned short h){
  union{unsigned u; float f;} c; c.u = ((unsigned)h)<<16; return c.f;
}
__device__ __forceinline__ unsigned short f2bf(float f){
  union{float f; unsigned u;} c; c.f = f;
  return (unsigned short)((c.u + 0x7fffu + ((c.u>>16)&1u))>>16);
}

// WcF[((i*12+kt)*3+t)*512 + lane*8 + j] = Wc[kt*16+(lane>>5)*8+j][t*32+(lane&31)]

// ---- ONE fused prep launch: weight-combine | bias | cast->xb | CSR rowptr
__global__ __launch_bounds__(256) void k_pre(
    const float* __restrict__ x,  const float* __restrict__ W0,
    const float* __restrict__ W1, const float* __restrict__ W2,
    const float* __restrict__ b0, const float* __restrict__ b1,
    const float* __restrict__ b2, const int* __restrict__ dst,
    unsigned short* __restrict__ WcF, float* __restrict__ cvec,
    float* __restrict__ dvec, unsigned short* __restrict__ xb,
    int* __restrict__ rs, int nN, int nE, int depth, int castBlocks)
{
  const int b = blockIdx.x, tid = threadIdx.x;
  const int nwc = depth*192;
  if (b < nwc){
    __shared__ float sm[96];
    int i = b/192, k = b%192;
    float s = 0.f;
    if (tid < 192){
      int c = tid % 96, jh = tid / 96;
      const float* w  = (k<96) ? (W1 + (size_t)i*9216 + (size_t)k*96)
                               : (W0 + (size_t)i*9216 + (size_t)(k-96)*96);
      const float* w2 = W2 + (size_t)i*18432 + (k<96 ? 0 : 9216);
      int j0 = jh*48;
      float s0=0.f,s1=0.f,s2=0.f,s3=0.f;
      for (int j=j0;j<j0+48;j+=4){
        s0 += w[j]   * w2[(j)*96 + c];
        s1 += w[j+1] * w2[(j+1)*96 + c];
        s2 += w[j+2] * w2[(j+2)*96 + c];
        s3 += w[j+3] * w2[(j+3)*96 + c];
      }
      s = (s0+s1)+(s2+s3);
      if (jh==1) sm[c] = s;
    }
    __syncthreads();
    if (tid < 96){
      float tot = s + sm[tid];
      int kt=k>>4, hfk=(k>>3)&1, jj=k&7;
      int t=tid>>5, cl=tid&31;
      WcF[(size_t)((i*12+kt)*3+t)*512 + (size_t)(hfk*32+cl)*8 + jj] = f2bf(tot);
    }
  } else if (b < nwc + depth){
    int i = b - nwc;
    if (tid < 96){
      const float* w2 = W2 + (size_t)i*18432;
      float s = b2[i*96+tid], d=0.f;
      for (int j=0;j<96;++j){
        s += b1[i*96+j]*w2[j*96+tid];
        d += b0[i*96+j]*w2[(96+j)*96+tid];
      }
      cvec[i*96+tid]=s; dvec[i*96+tid]=d;
    }
  } else if (b < nwc + depth + castBlocks){
    int t2 = (b - nwc - depth)*256 + tid;
    if (t2 >= nN*12) return;
    int n = t2/12, q = t2%12;
    const float4* src = reinterpret_cast<const float4*>(x + (size_t)n*96 + q*8);
    float4 f0 = src[0], f1 = src[1];
    uint4 o;
    o.x = (unsigned)f2bf(f0.x) | ((unsigned)f2bf(f0.y)<<16);
    o.y = (unsigned)f2bf(f0.z) | ((unsigned)f2bf(f0.w)<<16);
    o.z = (unsigned)f2bf(f1.x) | ((unsigned)f2bf(f1.y)<<16);
    o.w = (unsigned)f2bf(f1.z) | ((unsigned)f2bf(f1.w)<<16);
    *reinterpret_cast<uint4*>(xb + (size_t)n*96 + q*8) = o;
  } else {
    int n = (b - nwc - depth - castBlocks)*256 + tid;
    if (n > nN) return;
    int lo=0, hi=nE;
    while(lo<hi){int mid=(lo+hi)>>1; if(dst[mid]<n) lo=mid+1; else hi=mid;}
    rs[n]=lo;
  }
}

__device__ __forceinline__ void acc8(float* a, uint4 v){
  a[0] += bf2f((unsigned short)(v.x & 0xffffu));
  a[1] += bf2f((unsigned short)(v.x >> 16));
  a[2] += bf2f((unsigned short)(v.y & 0xffffu));
  a[3] += bf2f((unsigned short)(v.y >> 16));
  a[4] += bf2f((unsigned short)(v.z & 0xffffu));
  a[5] += bf2f((unsigned short)(v.z >> 16));
  a[6] += bf2f((unsigned short)(v.w & 0xffffu));
  a[7] += bf2f((unsigned short)(v.w >> 16));
}

// ---- fused per-layer kernel: one block (384 thr) per 32-row strip.
// Phase 1: gather strip's in-edges -> xa tile in LDS (fragment layout).
// Phase 2: wave 0 does 192x96 MFMA GEMM + bias/deg + rowstd + stores.
#define ECAP 2048
template<int LAST>
__global__ __launch_bounds__(384) void k_fused(
    const unsigned short* __restrict__ xb,
    const int* __restrict__ esrc, const int* __restrict__ rs,
    const unsigned short* __restrict__ WcF, const float* __restrict__ cvec,
    const float* __restrict__ dvec,
    float* __restrict__ outf, unsigned short* __restrict__ outb, int nN)
{
  __shared__ short aL[6*64*8];      // xa fragment tile, 6 KB
  __shared__ int   eL[ECAP];        // staged edge sources
  __shared__ int   rsL[33];

  const int tid = threadIdx.x;
  const int wid = blockIdx.x;       // strip id
  const int row0 = wid << 5;

  if (tid < 33){
    int nidx = row0 + tid; if (nidx > nN) nidx = nN;
    rsL[tid] = rs[nidx];
  }
  __syncthreads();
  const int base = rsL[0];
  const int cnt  = rsL[32] - base;

  const int nl = tid / 12;            // 0..31
  const int q  = tid - nl*12;         // 0..11
  const unsigned short* xq = xb + q*8;
  const int e0 = rsL[nl], e1 = rsL[nl+1];
  float a[8] = {0,0,0,0,0,0,0,0};

  for (int cb = base; cb < base + cnt; cb += ECAP){
    const int clen = min(ECAP, base + cnt - cb);
    if (cb != base) __syncthreads();            // eL reuse guard
    for (int i = tid; i < clen; i += 384) eL[i] = esrc[cb + i];
    __syncthreads();
    int e  = max(e0, cb);
    int hi = min(e1, cb + clen);
    const int* ep = eL - cb;
    for (; e+8 <= hi; e += 8){
      int s0=ep[e],s1=ep[e+1],s2=ep[e+2],s3=ep[e+3];
      int s4=ep[e+4],s5=ep[e+5],s6=ep[e+6],s7=ep[e+7];
      uint4 v0=*reinterpret_cast<const uint4*>(xq+(size_t)s0*96);
      uint4 v1=*reinterpret_cast<const uint4*>(xq+(size_t)s1*96);
      uint4 v2=*reinterpret_cast<const uint4*>(xq+(size_t)s2*96);
      uint4 v3=*reinterpret_cast<const uint4*>(xq+(size_t)s3*96);
      uint4 v4=*reinterpret_cast<const uint4*>(xq+(size_t)s4*96);
      uint4 v5=*reinterpret_cast<const uint4*>(xq+(size_t)s5*96);
      uint4 v6=*reinterpret_cast<const uint4*>(xq+(size_t)s6*96);
      uint4 v7=*reinterpret_cast<const uint4*>(xq+(size_t)s7*96);
      acc8(a,v0); acc8(a,v1); acc8(a,v2); acc8(a,v3);
      acc8(a,v4); acc8(a,v5); acc8(a,v6); acc8(a,v7);
    }
    for (; e+4 <= hi; e += 4){
      int s0=ep[e],s1=ep[e+1],s2=ep[e+2],s3=ep[e+3];
      uint4 v0=*reinterpret_cast<const uint4*>(xq+(size_t)s0*96);
      uint4 v1=*reinterpret_cast<const uint4*>(xq+(size_t)s1*96);
      uint4 v2=*reinterpret_cast<const uint4*>(xq+(size_t)s2*96);
      uint4 v3=*reinterpret_cast<const uint4*>(xq+(size_t)s3*96);
      acc8(a,v0); acc8(a,v1); acc8(a,v2); acc8(a,v3);
    }
    for (; e < hi; ++e){
      uint4 v=*reinterpret_cast<const uint4*>(xq+(size_t)ep[e]*96);
      acc8(a,v);
    }
  }

  {
    uint4 o;
    o.x=(unsigned)f2bf(a[0])|((unsigned)f2bf(a[1])<<16);
    o.y=(unsigned)f2bf(a[2])|((unsigned)f2bf(a[3])<<16);
    o.z=(unsigned)f2bf(a[4])|((unsigned)f2bf(a[5])<<16);
    o.w=(unsigned)f2bf(a[6])|((unsigned)f2bf(a[7])<<16);
    *reinterpret_cast<uint4*>(&aL[((q>>1)*64 + (q&1)*32 + nl)<<3]) = o;
  }
  __syncthreads();

  if (tid >= 64) return;

  // ---- phase 2: GEMM (wave 0). A-side x read directly from row-major xb
  // (divergent 16B loads — measured NEUTRAL vs fragment-coalesced, round 7).
  const int lane = tid;
  const int cl = lane & 31;
  const int hf = lane >> 5;

  int arow = row0 + cl; if (arow >= nN) arow = nN-1;
  const short8* xr  = reinterpret_cast<const short8*>(xb + (size_t)arow*96);
  const short8* aLs = reinterpret_cast<const short8*>(aL);
  const short8* wf  = reinterpret_cast<const short8*>(WcF);

  short8 afr[6];
  #pragma unroll
  for (int kt=0; kt<6; ++kt) afr[kt] = xr[kt*2 + hf];

  f32x16 acc[3];
  #pragma unroll
  for (int t=0;t<3;++t){
    #pragma unroll
    for (int i=0;i<16;++i) acc[t][i] = 0.f;
  }

  #pragma unroll
  for (int kt=0; kt<12; ++kt){
    short8 av = (kt < 6) ? afr[kt] : aLs[(kt-6)*64 + lane];
    #pragma unroll
    for (int t=0;t<3;++t){
      short8 b = wf[(kt*3+t)*64 + lane];
      acc[t] = __builtin_amdgcn_mfma_f32_32x32x16_bf16(av, b, acc[t], 0, 0, 0);
    }
  }

  float cv[3], dv[3];
  #pragma unroll
  for (int t=0;t<3;++t){ cv[t] = cvec[t*32+cl]; dv[t] = dvec[t*32+cl]; }

  #pragma unroll
  for (int r=0;r<16;++r){
    const int rl = (r&3) + ((r>>2)<<3) + (hf<<2);   // verified C/D row map
    const int rg = row0 + rl;
    const float dgv = (float)(rsL[rl+1] - rsL[rl]);
    float v0 = acc[0][r] + cv[0] + dgv*dv[0];
    float v1 = acc[1][r] + cv[1] + dgv*dv[1];
    float v2 = acc[2][r] + cv[2] + dgv*dv[2];
    float s  = v0+v1+v2;
    float s2 = v0*v0 + v1*v1 + v2*v2;
    #pragma unroll
    for (int m=1;m<32;m<<=1){ s += __shfl_xor(s,m,64); s2 += __shfl_xor(s2,m,64); }
    float var = (s2 - s*s*(1.0f/96.0f)) * (1.0f/95.0f);   // ddof=1
    float sc  = 1.0f / sqrtf(var);
    if (rg < nN){
      if (LAST){
        float* o = outf + (size_t)rg*96;
        o[cl] = v0*sc; o[32+cl] = v1*sc; o[64+cl] = v2*sc;
      } else {
        unsigned short* o = outb + (size_t)rg*96;
        o[cl] = f2bf(v0*sc); o[32+cl] = f2bf(v1*sc); o[64+cl] = f2bf(v2*sc);
      }
    }
  }
}

extern "C" void kernel_launch(void* const* d_in, const int* in_sizes, int n_in,
                              void* d_out, int out_size, void* d_ws, size_t ws_size,
                              hipStream_t stream)
{
  const float* x   = (const float*)d_in[0];
  const float* W0  = (const float*)d_in[1];
  const float* b0  = (const float*)d_in[2];
  const float* W1  = (const float*)d_in[3];
  const float* b1  = (const float*)d_in[4];
  const float* W2  = (const float*)d_in[5];
  const float* b2  = (const float*)d_in[6];
  const int* esrc  = (const int*)d_in[7];
  const int* edst  = (const int*)d_in[8];
  const int nN = in_sizes[0] / 96;
  const int nE = in_sizes[7];
  const int depth = in_sizes[1] / (96*96);
  float* out = (float*)d_out;

  const int nstrips = (nN+31)/32;

  char* p = (char*)d_ws;
  auto alloc = [&](size_t bytes)->char*{ char* r = p; p += (bytes + 255) & ~(size_t)255; return r; };
  unsigned short* WcF  = (unsigned short*)alloc((size_t)depth*12*3*512*2);
  float* cvec          = (float*)alloc((size_t)depth*96*4);
  float* dvec          = (float*)alloc((size_t)depth*96*4);
  int* rs              = (int*)alloc((size_t)(nN+1)*4);
  unsigned short* xb0  = (unsigned short*)alloc((size_t)nN*96*2);
  unsigned short* xb1  = (unsigned short*)alloc((size_t)nN*96*2);

  const int castBlocks = (nN*12+255)/256;
  const int rpBlocks   = (nN+1+255)/256;
  const int preGrid    = depth*192 + depth + castBlocks + rpBlocks;
  k_pre<<<dim3(preGrid), dim3(256), 0, stream>>>(
      x, W0, W1, W2, b0, b1, b2, edst, WcF, cvec, dvec, xb0, rs,
      nN, nE, depth, castBlocks);

  unsigned short* cur = xb0;
  unsigned short* nxt = xb1;
  for (int i=0; i<depth; ++i){
    if (i == depth-1){
      k_fused<1><<<dim3(nstrips), dim3(384), 0, stream>>>(
          cur, esrc, rs, WcF + (size_t)i*12*3*512, cvec + i*96, dvec + i*96,
          out, (unsigned short*)nullptr, nN);
    } else {
      k_fused<0><<<dim3(nstrips), dim3(384), 0, stream>>>(
          cur, esrc, rs, WcF + (size_t)i*12*3*512, cvec + i*96, dvec + i*96,
          (float*)nullptr, nxt, nN);
      unsigned short* t = cur; cur = nxt; nxt = t;
    }
  }
}